// Round 2
// baseline (45.915 us; speedup 1.0000x reference)
//
#include <hip/hip_runtime.h>

#define N_KPTS 10
#define BS 8
#define HH 180
#define WW 240
#define HW (HH * WW)
#define NPIX (BS * HW)
#define NT (NPIX / 4)                       // 86400 threads, 4 px each
#define COEFFS_SIZE (BS * (N_KPTS + 1) * HW)

typedef float f32x4 __attribute__((ext_vector_type(4)));

static __device__ __forceinline__ f32x4 splat(float x) {
    return (f32x4){x, x, x, x};
}
static __device__ __forceinline__ f32x4 vfma(f32x4 a, f32x4 b, f32x4 c) {
    f32x4 r;
    r.x = fmaf(a.x, b.x, c.x);
    r.y = fmaf(a.y, b.y, c.y);
    r.z = fmaf(a.z, b.z, c.z);
    r.w = fmaf(a.w, b.w, c.w);
    return r;
}

__global__ __launch_bounds__(256) void curve_integrator_kernel(
    const float* __restrict__ deriv,    // [BS][N_KPTS][HW]
    const float* __restrict__ blurry,   // [BS][1][HW]
    const float* __restrict__ kpts,     // [BS][N_KPTS][HW]
    float* __restrict__ out_coeffs,     // [BS][N_KPTS+1][HW]
    float* __restrict__ out_cache)      // [BS][N_KPTS][N_KPTS][HW]
{
    int t = blockIdx.x * blockDim.x + threadIdx.x;
    if (t >= NT) return;
    int p  = t * 4;                 // first pixel of this thread's quad
    int b  = p / HW;                // HW % 4 == 0 -> quad never crosses planes
    int hw = p - b * HW;

    const float* kp_base    = kpts  + (size_t)b * N_KPTS * HW + hw;
    const float* d_base     = deriv + (size_t)b * N_KPTS * HW + hw;
    float*       cache_base = out_cache + (size_t)b * N_KPTS * N_KPTS * HW + hw;

    f32x4 kp[N_KPTS];
#pragma unroll
    for (int i = 0; i < N_KPTS; ++i)
        kp[i] = __builtin_nontemporal_load((const f32x4*)(kp_base + (size_t)i * HW));

    f32x4 coeffs[N_KPTS];
#pragma unroll
    for (int o = 0; o < N_KPTS; ++o) coeffs[o] = splat(0.0f);

    const float rcp_tab[N_KPTS] = {
        1.0f, 1.0f/2.0f, 1.0f/3.0f, 1.0f/4.0f, 1.0f/5.0f,
        1.0f/6.0f, 1.0f/7.0f, 1.0f/8.0f, 1.0f/9.0f, 1.0f/10.0f
    };

#pragma unroll
    for (int i = 0; i < N_KPTS; ++i) {
        // c[k] = coeff of x^k in prod_{j != i} (x - kp[j]); all indices static
        f32x4 c[N_KPTS];
        c[0] = splat(1.0f);
#pragma unroll
        for (int k = 1; k < N_KPTS; ++k) c[k] = splat(0.0f);

        f32x4 denom = splat(1.0f);
#pragma unroll
        for (int j = 0; j < N_KPTS; ++j) {
            if (j == i) continue;                  // elided at compile time
            f32x4 nkpj = -kp[j];
            denom = denom * (kp[i] - kp[j]);
#pragma unroll
            for (int k = N_KPTS - 1; k >= 1; --k)
                c[k] = vfma(nkpj, c[k], c[k - 1]);
            c[0] = nkpj * c[0];
        }

        f32x4 inv = splat(1.0f) / denom;
        f32x4 di  = __builtin_nontemporal_load((const f32x4*)(d_base + (size_t)i * HW));
#pragma unroll
        for (int o = 0; o < N_KPTS; ++o) {
            f32x4 v = c[o] * (inv * splat(rcp_tab[o]));
            __builtin_nontemporal_store(v,
                (f32x4*)(cache_base + (size_t)(o * N_KPTS + i) * HW));
            coeffs[o] = vfma(v, di, coeffs[o]);
        }
    }

    // integral over [-1,1]: odd o only: 2*coeffs[o]/(o+2)
    f32x4 integral = coeffs[1] * splat(2.0f / 3.0f);
    integral = vfma(coeffs[3], splat(2.0f / 5.0f), integral);
    integral = vfma(coeffs[5], splat(2.0f / 7.0f), integral);
    integral = vfma(coeffs[7], splat(2.0f / 9.0f), integral);
    integral = vfma(coeffs[9], splat(2.0f / 11.0f), integral);

    f32x4 bl = __builtin_nontemporal_load((const f32x4*)(blurry + (size_t)b * HW + hw));
    f32x4 baseline = (bl * splat(2.0f) - integral) * splat(0.5f);

    float* oc = out_coeffs + (size_t)b * (N_KPTS + 1) * HW + hw;
    __builtin_nontemporal_store(baseline, (f32x4*)oc);
#pragma unroll
    for (int o = 0; o < N_KPTS; ++o)
        __builtin_nontemporal_store(coeffs[o], (f32x4*)(oc + (size_t)(o + 1) * HW));
}

extern "C" void kernel_launch(void* const* d_in, const int* in_sizes, int n_in,
                              void* d_out, int out_size, void* d_ws, size_t ws_size,
                              hipStream_t stream) {
    const float* deriv  = (const float*)d_in[0];
    const float* blurry = (const float*)d_in[1];
    const float* kpts   = (const float*)d_in[2];

    float* out_coeffs = (float*)d_out;                 // BS*(N_KPTS+1)*HW
    float* out_cache  = (float*)d_out + COEFFS_SIZE;   // BS*N_KPTS*N_KPTS*HW

    int threads = 256;
    int blocks  = (NT + threads - 1) / threads;        // 338
    curve_integrator_kernel<<<blocks, threads, 0, stream>>>(
        deriv, blurry, kpts, out_coeffs, out_cache);
}

// Round 3
// 36.624 us; speedup vs baseline: 1.2537x; 1.2537x over previous
//
#include <hip/hip_runtime.h>

#define N_KPTS 10
#define BS 8
#define HH 180
#define WW 240
#define HW (HH * WW)
#define NPIX (BS * HW)
#define COEFFS_SIZE (BS * (N_KPTS + 1) * HW)

__global__ __launch_bounds__(256) void curve_integrator_kernel(
    const float* __restrict__ deriv,    // [BS][N_KPTS][HW]
    const float* __restrict__ blurry,   // [BS][1][HW]
    const float* __restrict__ kpts,     // [BS][N_KPTS][HW]
    float* __restrict__ out_coeffs,     // [BS][N_KPTS+1][HW]
    float* __restrict__ out_cache)      // [BS][N_KPTS][N_KPTS][HW]
{
    int idx = blockIdx.x * blockDim.x + threadIdx.x;
    if (idx >= NPIX) return;
    int b  = idx / HW;
    int hw = idx - b * HW;

    const float* kp_base = kpts  + (size_t)b * N_KPTS * HW + hw;
    const float* d_base  = deriv + (size_t)b * N_KPTS * HW + hw;

    float kp[N_KPTS], dv[N_KPTS];
#pragma unroll
    for (int i = 0; i < N_KPTS; ++i) {
        kp[i] = kp_base[(size_t)i * HW];
        dv[i] = d_base[(size_t)i * HW];
    }

    float coeffs[N_KPTS];
#pragma unroll
    for (int o = 0; o < N_KPTS; ++o) coeffs[o] = 0.0f;

    float* cache_base = out_cache + (size_t)b * N_KPTS * N_KPTS * HW + hw;

    const float rcp_tab[N_KPTS] = {
        1.0f, 1.0f/2.0f, 1.0f/3.0f, 1.0f/4.0f, 1.0f/5.0f,
        1.0f/6.0f, 1.0f/7.0f, 1.0f/8.0f, 1.0f/9.0f, 1.0f/10.0f
    };

#pragma unroll
    for (int i = 0; i < N_KPTS; ++i) {
        // c[k] = coeff of x^k in prod_{j != i} (x - kp[j]); all indexing static
        float c[N_KPTS];
        c[0] = 1.0f;
#pragma unroll
        for (int k = 1; k < N_KPTS; ++k) c[k] = 0.0f;

        float denom = 1.0f;
#pragma unroll
        for (int j = 0; j < N_KPTS; ++j) {
            if (j == i) continue;            // elided at compile time
            float kpj = kp[j];
            denom *= (kp[i] - kpj);
#pragma unroll
            for (int k = N_KPTS - 1; k >= 1; --k)
                c[k] = fmaf(-kpj, c[k], c[k - 1]);
            c[0] = -kpj * c[0];
        }

        float inv = 1.0f / denom;
        float di  = dv[i];
#pragma unroll
        for (int o = 0; o < N_KPTS; ++o) {
            float v = c[o] * (inv * rcp_tab[o]);
            __builtin_nontemporal_store(v, cache_base + (size_t)(o * N_KPTS + i) * HW);
            coeffs[o] = fmaf(v, di, coeffs[o]);
        }
    }

    // integral over [-1,1]: odd o only: 2*coeffs[o]/(o+2)
    float integral = 2.0f * coeffs[1] / 3.0f;
    integral += 2.0f * coeffs[3] / 5.0f;
    integral += 2.0f * coeffs[5] / 7.0f;
    integral += 2.0f * coeffs[7] / 9.0f;
    integral += 2.0f * coeffs[9] / 11.0f;

    float baseline = (2.0f * blurry[(size_t)b * HW + hw] - integral) * 0.5f;

    float* oc = out_coeffs + (size_t)b * (N_KPTS + 1) * HW + hw;
    __builtin_nontemporal_store(baseline, oc);
#pragma unroll
    for (int o = 0; o < N_KPTS; ++o)
        __builtin_nontemporal_store(coeffs[o], oc + (size_t)(o + 1) * HW);
}

extern "C" void kernel_launch(void* const* d_in, const int* in_sizes, int n_in,
                              void* d_out, int out_size, void* d_ws, size_t ws_size,
                              hipStream_t stream) {
    const float* deriv  = (const float*)d_in[0];
    const float* blurry = (const float*)d_in[1];
    const float* kpts   = (const float*)d_in[2];

    float* out_coeffs = (float*)d_out;                 // BS*(N_KPTS+1)*HW
    float* out_cache  = (float*)d_out + COEFFS_SIZE;   // BS*N_KPTS*N_KPTS*HW

    int threads = 256;
    int blocks  = (NPIX + threads - 1) / threads;      // 1350
    curve_integrator_kernel<<<blocks, threads, 0, stream>>>(
        deriv, blurry, kpts, out_coeffs, out_cache);
}

// Round 4
// 32.579 us; speedup vs baseline: 1.4093x; 1.1241x over previous
//
#include <hip/hip_runtime.h>

#define N_KPTS 10
#define BS 8
#define HH 180
#define WW 240
#define HW (HH * WW)
#define NPIX (BS * HW)
#define NT2 (NPIX / 2)                      // 172800 threads, 2 px each
#define COEFFS_SIZE (BS * (N_KPTS + 1) * HW)

typedef float f32x2 __attribute__((ext_vector_type(2)));

static __device__ __forceinline__ f32x2 splat2(float x) { return (f32x2){x, x}; }
static __device__ __forceinline__ f32x2 vfma2(f32x2 a, f32x2 b, f32x2 c) {
    f32x2 r;
    r.x = fmaf(a.x, b.x, c.x);
    r.y = fmaf(a.y, b.y, c.y);
    return r;
}

__global__ __launch_bounds__(256) void curve_integrator_kernel(
    const float* __restrict__ deriv,    // [BS][N_KPTS][HW]
    const float* __restrict__ blurry,   // [BS][1][HW]
    const float* __restrict__ kpts,     // [BS][N_KPTS][HW]
    float* __restrict__ out_coeffs,     // [BS][N_KPTS+1][HW]
    float* __restrict__ out_cache)      // [BS][N_KPTS][N_KPTS][HW]
{
    int t = blockIdx.x * blockDim.x + threadIdx.x;
    if (t >= NT2) return;
    int p  = t * 2;                 // first pixel of this thread's pair
    int b  = p / HW;                // HW % 2 == 0 -> pair never crosses planes
    int hw = p - b * HW;

    const float* kp_base    = kpts  + (size_t)b * N_KPTS * HW + hw;
    const float* d_base     = deriv + (size_t)b * N_KPTS * HW + hw;
    float*       cache_base = out_cache + (size_t)b * N_KPTS * N_KPTS * HW + hw;

    f32x2 kp[N_KPTS];
#pragma unroll
    for (int i = 0; i < N_KPTS; ++i)
        kp[i] = *(const f32x2*)(kp_base + (size_t)i * HW);

    f32x2 coeffs[N_KPTS];
#pragma unroll
    for (int o = 0; o < N_KPTS; ++o) coeffs[o] = splat2(0.0f);

    const float rcp_tab[N_KPTS] = {
        1.0f, 1.0f/2.0f, 1.0f/3.0f, 1.0f/4.0f, 1.0f/5.0f,
        1.0f/6.0f, 1.0f/7.0f, 1.0f/8.0f, 1.0f/9.0f, 1.0f/10.0f
    };

#pragma unroll
    for (int i = 0; i < N_KPTS; ++i) {
        // c[k] = coeff of x^k in prod_{j != i} (x - kp[j]); all indexing static
        f32x2 c[N_KPTS];
        c[0] = splat2(1.0f);
#pragma unroll
        for (int k = 1; k < N_KPTS; ++k) c[k] = splat2(0.0f);

        f32x2 denom = splat2(1.0f);
#pragma unroll
        for (int j = 0; j < N_KPTS; ++j) {
            if (j == i) continue;                  // elided at compile time
            f32x2 nkpj = -kp[j];
            denom = denom * (kp[i] - kp[j]);
#pragma unroll
            for (int k = N_KPTS - 1; k >= 1; --k)
                c[k] = vfma2(nkpj, c[k], c[k - 1]);
            c[0] = nkpj * c[0];
        }

        f32x2 inv = splat2(1.0f) / denom;
        f32x2 di  = *(const f32x2*)(d_base + (size_t)i * HW);
#pragma unroll
        for (int o = 0; o < N_KPTS; ++o) {
            f32x2 v = c[o] * (inv * splat2(rcp_tab[o]));
            *(f32x2*)(cache_base + (size_t)(o * N_KPTS + i) * HW) = v;
            coeffs[o] = vfma2(v, di, coeffs[o]);
        }
    }

    // integral over [-1,1]: odd o only: 2*coeffs[o]/(o+2)
    f32x2 integral = coeffs[1] * splat2(2.0f / 3.0f);
    integral = vfma2(coeffs[3], splat2(2.0f / 5.0f), integral);
    integral = vfma2(coeffs[5], splat2(2.0f / 7.0f), integral);
    integral = vfma2(coeffs[7], splat2(2.0f / 9.0f), integral);
    integral = vfma2(coeffs[9], splat2(2.0f / 11.0f), integral);

    f32x2 bl = *(const f32x2*)(blurry + (size_t)b * HW + hw);
    f32x2 baseline = (bl * splat2(2.0f) - integral) * splat2(0.5f);

    float* oc = out_coeffs + (size_t)b * (N_KPTS + 1) * HW + hw;
    *(f32x2*)oc = baseline;
#pragma unroll
    for (int o = 0; o < N_KPTS; ++o)
        *(f32x2*)(oc + (size_t)(o + 1) * HW) = coeffs[o];
}

extern "C" void kernel_launch(void* const* d_in, const int* in_sizes, int n_in,
                              void* d_out, int out_size, void* d_ws, size_t ws_size,
                              hipStream_t stream) {
    const float* deriv  = (const float*)d_in[0];
    const float* blurry = (const float*)d_in[1];
    const float* kpts   = (const float*)d_in[2];

    float* out_coeffs = (float*)d_out;                 // BS*(N_KPTS+1)*HW
    float* out_cache  = (float*)d_out + COEFFS_SIZE;   // BS*N_KPTS*N_KPTS*HW

    int threads = 256;
    int blocks  = (NT2 + threads - 1) / threads;       // 675
    curve_integrator_kernel<<<blocks, threads, 0, stream>>>(
        deriv, blurry, kpts, out_coeffs, out_cache);
}